// Round 2
// baseline (207.795 us; speedup 1.0000x reference)
//
#include <hip/hip_runtime.h>

// Collapsed GCN (exact algebraic reduction of the 27-node graph):
//   y = x @ W0                                   [2048,1024]
//   z = lr(y+b0) + 2*lr(3y+b0) + lr(5y+b0)       (deg_in: node0=1, node2=node4=3, node6=5)
//   u = lr(z @ W1 + b1)                          [2048,512]
//   v = lr(u @ W2 + b2)                          [2048,256]
//   out = v @ Wc + bc                            [2048,1]
// lr = leaky_relu(., 0.2) = fmaxf(t, 0.2f*t)
//
// Only node 0 of each graph is read (h[::27]); its dependency cone is
// node1 <- {0,2,4,6} <- (all nodes share the same input row), so layer 0
// collapses to one GEMM + the degree-combine epilogue above.

__device__ __forceinline__ float lrelu(float t) { return fmaxf(t, 0.2f * t); }

// 64x64 tile, 256 threads, 4x4 per thread, K-step 16, double-buffered LDS,
// one barrier per K-step, global prefetch overlapped with compute.
// MODE 0: layer-0 degree-combine epilogue. MODE 1: bias + leaky relu.
template <int MODE>
__global__ __launch_bounds__(256, 2) void gemm_ep(const float* __restrict__ A,
                                                  const float* __restrict__ B,
                                                  const float* __restrict__ bias,
                                                  float* __restrict__ C,
                                                  int M, int N, int K) {
    // As padded to 68 floats/row: A-store banks become 2-way (free) instead of
    // 4-way; 68*4B = 272B = 17*16B keeps float4 reads aligned.
    __shared__ __align__(16) float As[2][16][68];  // As[buf][k][m]
    __shared__ __align__(16) float Bs[2][16][64];  // Bs[buf][k][n]

    const int tid = threadIdx.x;
    const int tx = tid & 15;        // 4 output cols each
    const int ty = tid >> 4;        // 4 output rows each
    const int bm = blockIdx.x * 64;
    const int bn = blockIdx.y * 64;

    // global->LDS mapping (one float4 of A and one of B per thread per K-step)
    const int ra = tid >> 2;        // 0..63 : A row in tile
    const int ka = (tid & 3) * 4;   // 0/4/8/12 : k offset
    const int kb = tid >> 4;        // 0..15 : B k-row in tile
    const int cb = (tid & 15) * 4;  // 0..60 : B col in tile

    const float* Ap = A + (size_t)(bm + ra) * K + ka;
    const float* Bp = B + (size_t)kb * N + bn + cb;

    float acc[4][4] = {};

    // stage tile 0
    float4 av = *(const float4*)(Ap);
    float4 bv = *(const float4*)(Bp);
    As[0][ka + 0][ra] = av.x;
    As[0][ka + 1][ra] = av.y;
    As[0][ka + 2][ra] = av.z;
    As[0][ka + 3][ra] = av.w;
    *(float4*)&Bs[0][kb][cb] = bv;

    const int T = K >> 4;
    for (int t = 0; t < T; ++t) {
        __syncthreads();  // tile t visible; prev readers of buf t&1^1 done
        const int cur = t & 1;
        if (t + 1 < T) {  // prefetch tile t+1 (in flight during compute)
            av = *(const float4*)(Ap + (t + 1) * 16);
            bv = *(const float4*)(Bp + (size_t)(t + 1) * 16 * N);
        }
#pragma unroll
        for (int k = 0; k < 16; ++k) {
            const float4 a = *(const float4*)&As[cur][k][ty * 4];
            const float4 b = *(const float4*)&Bs[cur][k][tx * 4];
            const float a4[4] = {a.x, a.y, a.z, a.w};
            const float b4[4] = {b.x, b.y, b.z, b.w};
#pragma unroll
            for (int i = 0; i < 4; ++i)
#pragma unroll
                for (int j = 0; j < 4; ++j)
                    acc[i][j] = fmaf(a4[i], b4[j], acc[i][j]);
        }
        if (t + 1 < T) {  // write tile t+1 into the other buffer (no barrier
                          // needed until top of next iteration)
            const int nxt = cur ^ 1;
            As[nxt][ka + 0][ra] = av.x;
            As[nxt][ka + 1][ra] = av.y;
            As[nxt][ka + 2][ra] = av.z;
            As[nxt][ka + 3][ra] = av.w;
            *(float4*)&Bs[nxt][kb][cb] = bv;
        }
    }

    const int col = bn + tx * 4;
    const float bia[4] = {bias[col], bias[col + 1], bias[col + 2], bias[col + 3]};
#pragma unroll
    for (int i = 0; i < 4; ++i) {
        float o[4];
#pragma unroll
        for (int j = 0; j < 4; ++j) {
            const float y = acc[i][j];
            if (MODE == 0) {
                o[j] = lrelu(y + bia[j]) + 2.f * lrelu(3.f * y + bia[j]) +
                       lrelu(5.f * y + bia[j]);
            } else {
                o[j] = lrelu(y + bia[j]);
            }
        }
        *(float4*)&C[(size_t)(bm + ty * 4 + i) * N + col] = *(const float4*)o;
    }
}

// out[r] = dot(V[r,0:256], Wc) + bc ; one wave per row.
__global__ __launch_bounds__(256) void head_k(const float* __restrict__ V,
                                              const float* __restrict__ Wc,
                                              const float* __restrict__ bc,
                                              float* __restrict__ out, int Brows) {
    const int gwave = (int)((blockIdx.x * 256u + threadIdx.x) >> 6);
    const int lane = threadIdx.x & 63;
    if (gwave >= Brows) return;
    const float4 v = *(const float4*)(V + (size_t)gwave * 256 + lane * 4);
    const float4 w = *(const float4*)(Wc + lane * 4);
    float s = v.x * w.x + v.y * w.y + v.z * w.z + v.w * w.w;
#pragma unroll
    for (int off = 32; off > 0; off >>= 1) s += __shfl_down(s, off, 64);
    if (lane == 0) out[gwave] = s + bc[0];
}

extern "C" void kernel_launch(void* const* d_in, const int* in_sizes, int n_in,
                              void* d_out, int out_size, void* d_ws, size_t ws_size,
                              hipStream_t stream) {
    const float* x  = (const float*)d_in[0];
    const float* W0 = (const float*)d_in[1];
    const float* b0 = (const float*)d_in[2];
    const float* W1 = (const float*)d_in[3];
    const float* b1 = (const float*)d_in[4];
    const float* W2 = (const float*)d_in[5];
    const float* b2 = (const float*)d_in[6];
    const float* Wc = (const float*)d_in[7];
    const float* bc = (const float*)d_in[8];
    float* out = (float*)d_out;

    const int Bn = 2048, D = 1024, C0 = 1024, C1 = 512, C2 = 256;

    float* Z = (float*)d_ws;              // [2048,1024] = 8 MB
    float* U = Z + (size_t)Bn * C0;       // [2048, 512] = 4 MB
    float* V = U + (size_t)Bn * C1;       // [2048, 256] = 2 MB  (needs 14 MB ws)

    gemm_ep<0><<<dim3(Bn / 64, C0 / 64), 256, 0, stream>>>(x, W0, b0, Z, Bn, C0, D);
    gemm_ep<1><<<dim3(Bn / 64, C1 / 64), 256, 0, stream>>>(Z, W1, b1, U, Bn, C1, C0);
    gemm_ep<1><<<dim3(Bn / 64, C2 / 64), 256, 0, stream>>>(U, W2, b2, V, Bn, C2, C1);
    head_k<<<(Bn * 64) / 256, 256, 0, stream>>>(V, Wc, bc, out, Bn);
}

// Round 3
// 134.813 us; speedup vs baseline: 1.5414x; 1.5414x over previous
//
#include <hip/hip_runtime.h>

// Collapsed GCN (exact algebraic reduction, verified on HW in round 2):
//   y = x @ W0;  z = lr(y+b0) + 2*lr(3y+b0) + lr(5y+b0)
//   u = lr(z @ W1 + b1);  v = lr(u @ W2 + b2);  out = v @ Wc + bc
// GEMMs run on bf16 MFMA with hi/lo split: a*b ~= ah*bh + ah*bl + al*bh
// (al*bl dropped, ~2^-18 relative => fp32-grade accuracy).

typedef __attribute__((ext_vector_type(8))) short short8;   // 8 bf16 = 4 VGPR
typedef __attribute__((ext_vector_type(4))) float f32x4;
typedef unsigned short u16;

__device__ __forceinline__ float lrelu(float t) { return fmaxf(t, 0.2f * t); }

__device__ __forceinline__ void split1(float f, u16& h, u16& l) {
    unsigned u = __builtin_bit_cast(unsigned, f);
    h = (u16)(u >> 16);                                   // truncate to bf16
    float fh = __builtin_bit_cast(float, (unsigned)(h) << 16);
    float fl = f - fh;                                    // exact residual
    l = (u16)(__builtin_bit_cast(unsigned, fl) >> 16);
}

__device__ __forceinline__ void gload_lds16(const void* g, void* l) {
    __builtin_amdgcn_global_load_lds(
        (const __attribute__((address_space(1))) void*)g,
        (__attribute__((address_space(3))) void*)l, 16, 0, 0);
}

// ---- split kernels -------------------------------------------------------
// x [R*C] f32 -> hi/lo bf16 planes (row-major preserved)
__global__ __launch_bounds__(256) void split_x(const float* __restrict__ x,
                                               u16* __restrict__ xh,
                                               u16* __restrict__ xl, int n4) {
    int i = blockIdx.x * 256 + threadIdx.x;
    if (i >= n4) return;
    float4 v = ((const float4*)x)[i];
    u16 h0, l0, h1, l1, h2, l2, h3, l3;
    split1(v.x, h0, l0); split1(v.y, h1, l1);
    split1(v.z, h2, l2); split1(v.w, h3, l3);
    ushort4 hv = {h0, h1, h2, h3}, lv = {l0, l1, l2, l3};
    ((ushort4*)xh)[i] = hv;
    ((ushort4*)xl)[i] = lv;
}

// W [K][N] f32 -> WT hi/lo bf16 [N][K]  (transpose via LDS 64x64 tile)
__global__ __launch_bounds__(256) void split_wT(const float* __restrict__ W,
                                                u16* __restrict__ wth,
                                                u16* __restrict__ wtl,
                                                int K, int N) {
    __shared__ float t[64][65];
    const int bk = blockIdx.x * 64, bn = blockIdx.y * 64;
    const int c = threadIdx.x & 63, r0 = threadIdx.x >> 6;  // r0 in 0..3
#pragma unroll
    for (int j = 0; j < 16; ++j) {
        int row = j * 4 + r0;
        t[row][c] = W[(size_t)(bk + row) * N + bn + c];
    }
    __syncthreads();
#pragma unroll
    for (int j = 0; j < 16; ++j) {
        int row = j * 4 + r0;              // output n-row offset
        float v = t[c][row];               // stride-65 read: conflict-free
        u16 h, l; split1(v, h, l);
        wth[(size_t)(bn + row) * K + bk + c] = h;
        wtl[(size_t)(bn + row) * K + bk + c] = l;
    }
}

// ---- split-bf16 MFMA GEMM ------------------------------------------------
// A planes [M][K] bf16 hi/lo, B planes [N][K] bf16 hi/lo (pre-transposed).
// 256 threads = 4 waves in 2x2; wave tile (BM/2)x(BN/2); BK=32.
// LDS tile rows are 64B (32 bf16); chunk (16B) at slot s stored at
// s ^ ((row>>1)&3)  => frag ds_read_b128 is bank-conflict-free.
// Staging: global_load_lds w16, linear LDS dest, pre-swizzled global source.
template <int BM, int BN, int MODE>
__global__ __launch_bounds__(256) void gemm_split(
    const u16* __restrict__ Ahi, const u16* __restrict__ Alo,
    const u16* __restrict__ Bhi, const u16* __restrict__ Blo,
    const float* __restrict__ bias,
    u16* __restrict__ Chi, u16* __restrict__ Clo, float* __restrict__ Cf,
    int M, int N, int K) {
    constexpr int BK = 32;
    constexpr int MF = BM / 32;          // m-frags per wave
    constexpr int NF = BN / 32;          // n-frags per wave
    constexpr int CH_A = BM * 4;         // 16B chunks per A plane
    constexpr int CH_B = BN * 4;
    constexpr int CH_TOT = 2 * CH_A + 2 * CH_B;
    constexpr int LOADS = CH_TOT / 256;  // global_load_lds per wave per step
    constexpr int HALF = CH_TOT * 16;    // bytes per LDS buffer
    constexpr int OFF_AHI = 0;
    constexpr int OFF_ALO = CH_A * 16;
    constexpr int OFF_BHI = 2 * CH_A * 16;
    constexpr int OFF_BLO = 2 * CH_A * 16 + CH_B * 16;

    __shared__ __align__(16) char smem[2 * HALF];

    const int tid = threadIdx.x;
    const int lane = tid & 63;
    const int wid = tid >> 6;
    const int wm = wid >> 1, wn = wid & 1;
    const int bm = blockIdx.x * BM;
    const int bn = blockIdx.y * BN;

    // per-lane fragment byte offsets (within plane), swizzled
    int a_off[MF], b_off[NF];
#pragma unroll
    for (int mi = 0; mi < MF; ++mi) {
        int r = wm * (BM / 2) + mi * 16 + (lane & 15);
        int slot = (lane >> 4) ^ ((r >> 1) & 3);
        a_off[mi] = r * 64 + slot * 16;
    }
#pragma unroll
    for (int ni = 0; ni < NF; ++ni) {
        int r = wn * (BN / 2) + ni * 16 + (lane & 15);
        int slot = (lane >> 4) ^ ((r >> 1) & 3);
        b_off[ni] = r * 64 + slot * 16;
    }

    f32x4 acc[MF][NF];
#pragma unroll
    for (int mi = 0; mi < MF; ++mi)
#pragma unroll
        for (int ni = 0; ni < NF; ++ni) acc[mi][ni] = {0.f, 0.f, 0.f, 0.f};

    auto stage = [&](int buf, int t) {
        const int k0 = t * BK;
#pragma unroll
        for (int j = 0; j < LOADS; ++j) {
            const int c0 = wid * (LOADS * 64) + j * 64;  // wave-uniform
            const u16* base; int pstart, row0;
            if (c0 < CH_A)                { base = Ahi; pstart = 0;             row0 = bm; }
            else if (c0 < 2 * CH_A)       { base = Alo; pstart = CH_A;          row0 = bm; }
            else if (c0 < 2 * CH_A + CH_B){ base = Bhi; pstart = 2 * CH_A;      row0 = bn; }
            else                          { base = Blo; pstart = 2 * CH_A + CH_B; row0 = bn; }
            const int cp = c0 - pstart + lane;
            const int r = cp >> 2;
            const int s = (cp & 3) ^ ((r >> 1) & 3);     // inverse-swizzled src
            const u16* src = base + (size_t)(row0 + r) * K + k0 + 8 * s;
            gload_lds16(src, smem + buf * HALF + c0 * 16);
        }
    };

    const int T = K / BK;
    stage(0, 0);
    for (int t = 0; t < T; ++t) {
        __syncthreads();  // compiler drains vmcnt+lgkmcnt: buf[t&1] ready
        const int buf = t & 1;
        if (t + 1 < T) stage(buf ^ 1, t + 1);
        const char* sb = smem + buf * HALF;
        short8 ah[MF], al[MF], bh[NF], bl[NF];
#pragma unroll
        for (int mi = 0; mi < MF; ++mi) {
            ah[mi] = *(const short8*)(sb + OFF_AHI + a_off[mi]);
            al[mi] = *(const short8*)(sb + OFF_ALO + a_off[mi]);
        }
#pragma unroll
        for (int ni = 0; ni < NF; ++ni) {
            bh[ni] = *(const short8*)(sb + OFF_BHI + b_off[ni]);
            bl[ni] = *(const short8*)(sb + OFF_BLO + b_off[ni]);
        }
#pragma unroll
        for (int mi = 0; mi < MF; ++mi)
#pragma unroll
            for (int ni = 0; ni < NF; ++ni) {
                acc[mi][ni] = __builtin_amdgcn_mfma_f32_16x16x32_bf16(ah[mi], bh[ni], acc[mi][ni], 0, 0, 0);
                acc[mi][ni] = __builtin_amdgcn_mfma_f32_16x16x32_bf16(ah[mi], bl[ni], acc[mi][ni], 0, 0, 0);
                acc[mi][ni] = __builtin_amdgcn_mfma_f32_16x16x32_bf16(al[mi], bh[ni], acc[mi][ni], 0, 0, 0);
            }
    }

    // epilogue: D row=(lane>>4)*4+reg, col=lane&15 (m89-verified)
#pragma unroll
    for (int mi = 0; mi < MF; ++mi)
#pragma unroll
        for (int ni = 0; ni < NF; ++ni) {
            const int gcol = bn + wn * (BN / 2) + ni * 16 + (lane & 15);
            const float bv = bias[gcol];
            const f32x4 a = acc[mi][ni];
#pragma unroll
            for (int r = 0; r < 4; ++r) {
                const int grow = bm + wm * (BM / 2) + mi * 16 + (lane >> 4) * 4 + r;
                const float y = a[r];
                float z;
                if constexpr (MODE == 0)
                    z = lrelu(y + bv) + 2.f * lrelu(3.f * y + bv) + lrelu(5.f * y + bv);
                else
                    z = lrelu(y + bv);
                if constexpr (MODE == 2) {
                    Cf[(size_t)grow * N + gcol] = z;
                } else {
                    u16 h, l; split1(z, h, l);
                    Chi[(size_t)grow * N + gcol] = h;
                    Clo[(size_t)grow * N + gcol] = l;
                }
            }
        }
}

// out[r] = dot(V[r,0:256], Wc) + bc ; one wave per row.
__global__ __launch_bounds__(256) void head_k(const float* __restrict__ V,
                                              const float* __restrict__ Wc,
                                              const float* __restrict__ bc,
                                              float* __restrict__ out, int Brows) {
    const int gwave = (int)((blockIdx.x * 256u + threadIdx.x) >> 6);
    const int lane = threadIdx.x & 63;
    if (gwave >= Brows) return;
    const float4 v = *(const float4*)(V + (size_t)gwave * 256 + lane * 4);
    const float4 w = *(const float4*)(Wc + lane * 4);
    float s = v.x * w.x + v.y * w.y + v.z * w.z + v.w * w.w;
#pragma unroll
    for (int off = 32; off > 0; off >>= 1) s += __shfl_down(s, off, 64);
    if (lane == 0) out[gwave] = s + bc[0];
}

extern "C" void kernel_launch(void* const* d_in, const int* in_sizes, int n_in,
                              void* d_out, int out_size, void* d_ws, size_t ws_size,
                              hipStream_t stream) {
    const float* x  = (const float*)d_in[0];
    const float* W0 = (const float*)d_in[1];
    const float* b0 = (const float*)d_in[2];
    const float* W1 = (const float*)d_in[3];
    const float* b1 = (const float*)d_in[4];
    const float* W2 = (const float*)d_in[5];
    const float* b2 = (const float*)d_in[6];
    const float* Wc = (const float*)d_in[7];
    const float* bc = (const float*)d_in[8];
    float* out = (float*)d_out;

    const int Bn = 2048;

    // workspace layout (bytes); peak 22.5 MB
    char* w = (char*)d_ws;
    u16* XHI  = (u16*)(w + 0);          // 4 MB
    u16* XLO  = (u16*)(w + 4194304);    // 4 MB
    u16* W0TH = (u16*)(w + 8388608);    // 2 MB
    u16* W0TL = (u16*)(w + 10485760);   // 2 MB
    u16* W1TH = (u16*)(w + 12582912);   // 1 MB
    u16* W1TL = (u16*)(w + 13631488);   // 1 MB
    u16* W2TH = (u16*)(w + 14680064);   // 256 KB
    u16* W2TL = (u16*)(w + 14942208);   // 256 KB
    u16* ZHI  = (u16*)(w + 15204352);   // 4 MB
    u16* ZLO  = (u16*)(w + 19398656);   // 4 MB
    u16* UHI  = (u16*)(w + 0);          // reuse X region (X dead after L0)
    u16* ULO  = (u16*)(w + 2097152);
    float* V  = (float*)(w + 15204352); // reuse Z region (Z dead after L1)

    split_x<<<2048, 256, 0, stream>>>(x, XHI, XLO, Bn * 1024 / 4);
    split_wT<<<dim3(16, 16), 256, 0, stream>>>(W0, W0TH, W0TL, 1024, 1024);
    split_wT<<<dim3(16, 8),  256, 0, stream>>>(W1, W1TH, W1TL, 1024, 512);
    split_wT<<<dim3(8, 4),   256, 0, stream>>>(W2, W2TH, W2TL, 512, 256);

    // L0: [2048,1024] = x[2048,1024] @ W0 ; grid 16x16 = 256 blocks
    gemm_split<128, 64, 0><<<dim3(16, 16), 256, 0, stream>>>(
        XHI, XLO, W0TH, W0TL, b0, ZHI, ZLO, nullptr, Bn, 1024, 1024);
    // L1: [2048,512] ; grid 32x8 = 256 blocks
    gemm_split<64, 64, 1><<<dim3(32, 8), 256, 0, stream>>>(
        ZHI, ZLO, W1TH, W1TL, b1, UHI, ULO, nullptr, Bn, 512, 1024);
    // L2: [2048,256] ; grid 32x8 = 256 blocks
    gemm_split<64, 32, 2><<<dim3(32, 8), 256, 0, stream>>>(
        UHI, ULO, W2TH, W2TL, b2, nullptr, nullptr, V, Bn, 256, 512);

    head_k<<<(Bn * 64) / 256, 256, 0, stream>>>(V, Wc, bc, out, Bn);
}

// Round 6
// 123.648 us; speedup vs baseline: 1.6805x; 1.0903x over previous
//
#include <hip/hip_runtime.h>

// Collapsed GCN (exact algebraic reduction, HW-verified rounds 2-3):
//   y = x @ W0;  z = lr(y+b0) + 2*lr(3y+b0) + lr(5y+b0)   (deg: n0=1, n2=n4=3, n6=5)
//   u = lr(z @ W1 + b1);  v = lr(u @ W2 + b2);  out = v @ Wc + bc
// GEMMs on bf16 MFMA with hi/lo split: a*b ~= ah*bh + ah*bl + al*bh.

typedef __attribute__((ext_vector_type(8))) short short8;   // 8 bf16 = 4 VGPR
typedef __attribute__((ext_vector_type(4))) float f32x4;
typedef unsigned short u16;

__device__ __forceinline__ float lrelu(float t) { return fmaxf(t, 0.2f * t); }

__device__ __forceinline__ void split1(float f, u16& h, u16& l) {
    unsigned u = __builtin_bit_cast(unsigned, f);
    h = (u16)(u >> 16);                                   // truncate to bf16
    float fh = __builtin_bit_cast(float, (unsigned)(h) << 16);
    float fl = f - fh;                                    // exact residual
    l = (u16)(__builtin_bit_cast(unsigned, fl) >> 16);
}

__device__ __forceinline__ void gload_lds16(const void* g, void* l) {
    __builtin_amdgcn_global_load_lds(
        (const __attribute__((address_space(1))) void*)g,
        (__attribute__((address_space(3))) void*)l, 16, 0, 0);
}

// ---- fused preprocessing: split x, transpose+split W0/W1/W2, init out -----
__device__ __forceinline__ void wT_tile(const float* __restrict__ W,
                                        u16* __restrict__ wth, u16* __restrict__ wtl,
                                        int K, int N, int bk, int bn,
                                        float (*t)[65], int tid) {
    const int c = tid & 63, r0 = tid >> 6;  // r0 in 0..3
#pragma unroll
    for (int j = 0; j < 16; ++j) {
        int row = j * 4 + r0;
        t[row][c] = W[(size_t)(bk + row) * N + bn + c];
    }
    __syncthreads();
#pragma unroll
    for (int j = 0; j < 16; ++j) {
        int row = j * 4 + r0;
        float v = t[c][row];               // stride-65: conflict-free
        u16 h, l; split1(v, h, l);
        wth[(size_t)(bn + row) * K + bk + c] = h;
        wtl[(size_t)(bn + row) * K + bk + c] = l;
    }
}

__global__ __launch_bounds__(256) void prep(
    const float* __restrict__ x, const float* __restrict__ W0,
    const float* __restrict__ W1, const float* __restrict__ W2,
    const float* __restrict__ bc,
    u16* __restrict__ XHI, u16* __restrict__ XLO,
    u16* __restrict__ W0TH, u16* __restrict__ W0TL,
    u16* __restrict__ W1TH, u16* __restrict__ W1TL,
    u16* __restrict__ W2TH, u16* __restrict__ W2TL,
    float* __restrict__ outp) {
    __shared__ float t[64][65];
    const int b = blockIdx.x, tid = threadIdx.x;
    if (b < 2048) {                          // split x: 2048*1024 f32
        const int i = b * 256 + tid;
        float4 v = ((const float4*)x)[i];
        u16 h0, l0, h1, l1, h2, l2, h3, l3;
        split1(v.x, h0, l0); split1(v.y, h1, l1);
        split1(v.z, h2, l2); split1(v.w, h3, l3);
        ushort4 hv = {h0, h1, h2, h3}, lv = {l0, l1, l2, l3};
        ((ushort4*)XHI)[i] = hv;
        ((ushort4*)XLO)[i] = lv;
    } else if (b < 2304) {                   // W0^T: 1024x1024, 16x16 tiles
        const int idx = b - 2048;
        wT_tile(W0, W0TH, W0TL, 1024, 1024, (idx & 15) * 64, (idx >> 4) * 64, t, tid);
    } else if (b < 2432) {                   // W1^T: 1024x512, 16x8 tiles
        const int idx = b - 2304;
        wT_tile(W1, W1TH, W1TL, 1024, 512, (idx & 15) * 64, (idx >> 4) * 64, t, tid);
    } else if (b < 2464) {                   // W2^T: 512x256, 8x4 tiles
        const int idx = b - 2432;
        wT_tile(W2, W2TH, W2TL, 512, 256, (idx & 7) * 64, (idx >> 3) * 64, t, tid);
    } else {                                 // out[r] = bc
        const float bv = bc[0];
#pragma unroll
        for (int j = 0; j < 8; ++j) outp[tid * 8 + j] = bv;
    }
}

// ---- split-bf16 MFMA GEMM -------------------------------------------------
// A planes [M][K], B planes [N][K] bf16 hi/lo. 256 threads = 4 waves (2x2),
// wave tile (BM/2)x(BN/2), BK=32, double-buffered LDS, 1 barrier/K-step.
// LDS rows 64B (32 bf16); 16B chunk slot s stored at s ^ ((row>>1)&3)
// (inverse-swizzled global source, linear global_load_lds dest).
// MODE 0: degree-combine epilogue + split-store.
// MODE 1: bias+lrelu + split-store.
// MODE 3: bias+lrelu, dot with Wc, atomicAdd into outp (head fused).
template <int BM, int BN, int MODE>
__global__ __launch_bounds__(256, 2) void gemm_split(
    const u16* __restrict__ Ahi, const u16* __restrict__ Alo,
    const u16* __restrict__ Bhi, const u16* __restrict__ Blo,
    const float* __restrict__ bias,
    u16* __restrict__ Chi, u16* __restrict__ Clo,
    const float* __restrict__ Wc, float* __restrict__ outp,
    int M, int N, int K) {
    constexpr int BK = 32;
    constexpr int MF = BM / 32;
    constexpr int NF = BN / 32;
    constexpr int CH_A = BM * 4;          // 16B chunks per A plane per step
    constexpr int CH_B = BN * 4;
    constexpr int CH_TOT = 2 * CH_A + 2 * CH_B;
    constexpr int LOADS = CH_TOT / 256;
    constexpr int HALF = CH_TOT * 16;
    constexpr int OFF_ALO = CH_A * 16;
    constexpr int OFF_BHI = 2 * CH_A * 16;
    constexpr int OFF_BLO = 2 * CH_A * 16 + CH_B * 16;

    __shared__ __align__(16) char smem[2 * HALF];

    const int tid = threadIdx.x;
    const int lane = tid & 63;
    const int wid = tid >> 6;
    const int wm = wid >> 1, wn = wid & 1;
    const int bm = blockIdx.x * BM;
    const int bn = blockIdx.y * BN;

    int a_off[MF], b_off[NF];
#pragma unroll
    for (int mi = 0; mi < MF; ++mi) {
        int r = wm * (BM / 2) + mi * 16 + (lane & 15);
        a_off[mi] = r * 64 + (((lane >> 4) ^ ((r >> 1) & 3)) * 16);
    }
#pragma unroll
    for (int ni = 0; ni < NF; ++ni) {
        int r = wn * (BN / 2) + ni * 16 + (lane & 15);
        b_off[ni] = r * 64 + (((lane >> 4) ^ ((r >> 1) & 3)) * 16);
    }

    f32x4 acc[MF][NF];
#pragma unroll
    for (int mi = 0; mi < MF; ++mi)
#pragma unroll
        for (int ni = 0; ni < NF; ++ni) acc[mi][ni] = {0.f, 0.f, 0.f, 0.f};

    auto stage = [&](int buf, int t) {
        const int k0 = t * BK;
#pragma unroll
        for (int j = 0; j < LOADS; ++j) {
            const int c0 = wid * (LOADS * 64) + j * 64;  // wave-uniform
            const u16* base; int pstart, row0;
            if (c0 < CH_A)                 { base = Ahi; pstart = 0;              row0 = bm; }
            else if (c0 < 2 * CH_A)        { base = Alo; pstart = CH_A;           row0 = bm; }
            else if (c0 < 2 * CH_A + CH_B) { base = Bhi; pstart = 2 * CH_A;       row0 = bn; }
            else                           { base = Blo; pstart = 2 * CH_A + CH_B; row0 = bn; }
            const int cp = c0 - pstart + lane;
            const int r = cp >> 2;
            const int s = (cp & 3) ^ ((r >> 1) & 3);     // inverse-swizzled src
            const u16* src = base + (size_t)(row0 + r) * K + k0 + 8 * s;
            gload_lds16(src, smem + buf * HALF + c0 * 16);
        }
    };

    const int T = K / BK;
    stage(0, 0);
    for (int t = 0; t < T; ++t) {
        __syncthreads();  // drains vmcnt+lgkmcnt: buf[t&1] ready
        const int buf = t & 1;
        if (t + 1 < T) stage(buf ^ 1, t + 1);
        const char* sb = smem + buf * HALF;
        short8 ah[MF], al[MF], bh[NF], bl[NF];
#pragma unroll
        for (int mi = 0; mi < MF; ++mi) {
            ah[mi] = *(const short8*)(sb + a_off[mi]);
            al[mi] = *(const short8*)(sb + OFF_ALO + a_off[mi]);
        }
#pragma unroll
        for (int ni = 0; ni < NF; ++ni) {
            bh[ni] = *(const short8*)(sb + OFF_BHI + b_off[ni]);
            bl[ni] = *(const short8*)(sb + OFF_BLO + b_off[ni]);
        }
#pragma unroll
        for (int mi = 0; mi < MF; ++mi)
#pragma unroll
            for (int ni = 0; ni < NF; ++ni) {
                acc[mi][ni] = __builtin_amdgcn_mfma_f32_16x16x32_bf16(ah[mi], bh[ni], acc[mi][ni], 0, 0, 0);
                acc[mi][ni] = __builtin_amdgcn_mfma_f32_16x16x32_bf16(ah[mi], bl[ni], acc[mi][ni], 0, 0, 0);
                acc[mi][ni] = __builtin_amdgcn_mfma_f32_16x16x32_bf16(al[mi], bh[ni], acc[mi][ni], 0, 0, 0);
            }
    }

    // epilogue: D col=lane&15, row=(lane>>4)*4+reg (m89-verified)
#pragma unroll
    for (int mi = 0; mi < MF; ++mi) {
        float hp[4] = {0.f, 0.f, 0.f, 0.f};  // MODE 3 head partials per reg-row
#pragma unroll
        for (int ni = 0; ni < NF; ++ni) {
            const int gcol = bn + wn * (BN / 2) + ni * 16 + (lane & 15);
            const float bv = bias[gcol];
            const f32x4 a = acc[mi][ni];
#pragma unroll
            for (int r = 0; r < 4; ++r) {
                const int grow = bm + wm * (BM / 2) + mi * 16 + (lane >> 4) * 4 + r;
                const float y = a[r];
                float z;
                if constexpr (MODE == 0)
                    z = lrelu(y + bv) + 2.f * lrelu(3.f * y + bv) + lrelu(5.f * y + bv);
                else
                    z = lrelu(y + bv);
                if constexpr (MODE == 3) {
                    hp[r] += z * Wc[gcol];
                } else {
                    u16 h, l; split1(z, h, l);
                    Chi[(size_t)grow * N + gcol] = h;
                    Clo[(size_t)grow * N + gcol] = l;
                }
            }
        }
        if constexpr (MODE == 3) {
            // reduce over the 16 lanes of each (lane>>4) group, then 1 atomic/row
#pragma unroll
            for (int r = 0; r < 4; ++r) {
#pragma unroll
                for (int o = 1; o < 16; o <<= 1) hp[r] += __shfl_xor(hp[r], o, 64);
            }
            if ((lane & 15) == 0) {
#pragma unroll
                for (int r = 0; r < 4; ++r) {
                    const int grow = bm + wm * (BM / 2) + mi * 16 + (lane >> 4) * 4 + r;
                    atomicAdd(outp + grow, hp[r]);
                }
            }
        }
    }
}

extern "C" void kernel_launch(void* const* d_in, const int* in_sizes, int n_in,
                              void* d_out, int out_size, void* d_ws, size_t ws_size,
                              hipStream_t stream) {
    const float* x  = (const float*)d_in[0];
    const float* W0 = (const float*)d_in[1];
    const float* b0 = (const float*)d_in[2];
    const float* W1 = (const float*)d_in[3];
    const float* b1 = (const float*)d_in[4];
    const float* W2 = (const float*)d_in[5];
    const float* b2 = (const float*)d_in[6];
    const float* Wc = (const float*)d_in[7];
    const float* bc = (const float*)d_in[8];
    float* out = (float*)d_out;

    const int Bn = 2048;

    char* w = (char*)d_ws;                 // peak ~23.6 MB
    u16* XHI  = (u16*)(w + 0);             // 4 MB
    u16* XLO  = (u16*)(w + 4194304);       // 4 MB
    u16* W0TH = (u16*)(w + 8388608);       // 2 MB
    u16* W0TL = (u16*)(w + 10485760);      // 2 MB
    u16* W1TH = (u16*)(w + 12582912);      // 1 MB
    u16* W1TL = (u16*)(w + 13631488);      // 1 MB
    u16* W2TH = (u16*)(w + 14680064);      // 256 KB
    u16* W2TL = (u16*)(w + 14942208);      // 256 KB
    u16* ZHI  = (u16*)(w + 15204352);      // 4 MB
    u16* ZLO  = (u16*)(w + 19398656);      // 4 MB
    u16* UHI  = (u16*)(w + 0);             // reuse X (dead after L0)
    u16* ULO  = (u16*)(w + 2097152);

    prep<<<2465, 256, 0, stream>>>(x, W0, W1, W2, bc, XHI, XLO, W0TH, W0TL,
                                   W1TH, W1TL, W2TH, W2TL, out);

    // L0: [2048,1024], K=1024 ; 64x64 tiles -> 512 blocks (2/CU)
    gemm_split<64, 64, 0><<<dim3(32, 16), 256, 0, stream>>>(
        XHI, XLO, W0TH, W0TL, b0, ZHI, ZLO, nullptr, nullptr, Bn, 1024, 1024);
    // L1: [2048,512], K=1024 ; 64x32 tiles -> 512 blocks
    gemm_split<64, 32, 1><<<dim3(32, 16), 256, 0, stream>>>(
        ZHI, ZLO, W1TH, W1TL, b1, UHI, ULO, nullptr, nullptr, Bn, 512, 1024);
    // L2+head: [2048,256], K=512 ; 64x32 tiles -> 256 blocks, atomics into out
    gemm_split<64, 32, 3><<<dim3(32, 8), 256, 0, stream>>>(
        UHI, ULO, W2TH, W2TL, b2, nullptr, nullptr, Wc, out, Bn, 256, 512);
}

// Round 10
// 122.278 us; speedup vs baseline: 1.6994x; 1.0112x over previous
//
#include <hip/hip_runtime.h>

// Collapsed GCN (exact algebraic reduction, HW-verified rounds 2-6):
//   y = x @ W0;  z = lr(y+b0) + 2*lr(3y+b0) + lr(5y+b0)   (deg: n0=1, n2=n4=3, n6=5)
//   u = lr(z @ W1 + b1);  v = lr(u @ W2 + b2);  out = v @ Wc + bc
// GEMMs on bf16 MFMA with hi/lo split: a*b ~= ah*bh + ah*bl + al*bh.
//
// NOTE: BK=64 variant (round 8) failed post-timing re-validation with a
// warm-up-dependent divergence; this is the BK=32 configuration that passed
// the full harness (round 6, 123.6 us).

typedef __attribute__((ext_vector_type(8))) short short8;   // 8 bf16 = 4 VGPR
typedef __attribute__((ext_vector_type(4))) float f32x4;
typedef unsigned short u16;

__device__ __forceinline__ float lrelu(float t) { return fmaxf(t, 0.2f * t); }

__device__ __forceinline__ void split1(float f, u16& h, u16& l) {
    unsigned u = __builtin_bit_cast(unsigned, f);
    h = (u16)(u >> 16);                                   // truncate to bf16
    float fh = __builtin_bit_cast(float, (unsigned)(h) << 16);
    float fl = f - fh;                                    // exact residual
    l = (u16)(__builtin_bit_cast(unsigned, fl) >> 16);
}

__device__ __forceinline__ void gload_lds16(const void* g, void* l) {
    __builtin_amdgcn_global_load_lds(
        (const __attribute__((address_space(1))) void*)g,
        (__attribute__((address_space(3))) void*)l, 16, 0, 0);
}

// ---- fused preprocessing: split x, transpose+split W0/W1/W2, init out -----
__device__ __forceinline__ void wT_tile(const float* __restrict__ W,
                                        u16* __restrict__ wth, u16* __restrict__ wtl,
                                        int K, int N, int bk, int bn,
                                        float (*t)[65], int tid) {
    const int c = tid & 63, r0 = tid >> 6;  // r0 in 0..3
#pragma unroll
    for (int j = 0; j < 16; ++j) {
        int row = j * 4 + r0;
        t[row][c] = W[(size_t)(bk + row) * N + bn + c];
    }
    __syncthreads();
#pragma unroll
    for (int j = 0; j < 16; ++j) {
        int row = j * 4 + r0;
        float v = t[c][row];               // stride-65: conflict-free
        u16 h, l; split1(v, h, l);
        wth[(size_t)(bn + row) * K + bk + c] = h;
        wtl[(size_t)(bn + row) * K + bk + c] = l;
    }
}

__global__ __launch_bounds__(256) void prep(
    const float* __restrict__ x, const float* __restrict__ W0,
    const float* __restrict__ W1, const float* __restrict__ W2,
    const float* __restrict__ bc,
    u16* __restrict__ XHI, u16* __restrict__ XLO,
    u16* __restrict__ W0TH, u16* __restrict__ W0TL,
    u16* __restrict__ W1TH, u16* __restrict__ W1TL,
    u16* __restrict__ W2TH, u16* __restrict__ W2TL,
    float* __restrict__ outp) {
    __shared__ float t[64][65];
    const int b = blockIdx.x, tid = threadIdx.x;
    if (b < 2048) {                          // split x: 2048*1024 f32
        const int i = b * 256 + tid;
        float4 v = ((const float4*)x)[i];
        u16 h0, l0, h1, l1, h2, l2, h3, l3;
        split1(v.x, h0, l0); split1(v.y, h1, l1);
        split1(v.z, h2, l2); split1(v.w, h3, l3);
        ushort4 hv = {h0, h1, h2, h3}, lv = {l0, l1, l2, l3};
        ((ushort4*)XHI)[i] = hv;
        ((ushort4*)XLO)[i] = lv;
    } else if (b < 2304) {                   // W0^T: 1024x1024, 16x16 tiles
        const int idx = b - 2048;
        wT_tile(W0, W0TH, W0TL, 1024, 1024, (idx & 15) * 64, (idx >> 4) * 64, t, tid);
    } else if (b < 2432) {                   // W1^T: 1024x512, 16x8 tiles
        const int idx = b - 2304;
        wT_tile(W1, W1TH, W1TL, 1024, 512, (idx & 15) * 64, (idx >> 4) * 64, t, tid);
    } else if (b < 2464) {                   // W2^T: 512x256, 8x4 tiles
        const int idx = b - 2432;
        wT_tile(W2, W2TH, W2TL, 512, 256, (idx & 7) * 64, (idx >> 3) * 64, t, tid);
    } else {                                 // out[r] = bc
        const float bv = bc[0];
#pragma unroll
        for (int j = 0; j < 8; ++j) outp[tid * 8 + j] = bv;
    }
}

// ---- split-bf16 MFMA GEMM -------------------------------------------------
// A planes [M][K], B planes [N][K] bf16 hi/lo. 256 threads = 4 waves (2x2),
// wave tile (BM/2)x(BN/2), BK=32, double-buffered LDS, 1 barrier/K-step.
// LDS rows 64B (32 bf16); 16B chunk slot s stored at s ^ ((row>>1)&3)
// (inverse-swizzled global source, linear global_load_lds dest).
// MODE 0: degree-combine epilogue + split-store.
// MODE 1: bias+lrelu + split-store.
// MODE 3: bias+lrelu, dot with Wc, atomicAdd into outp (head fused).
template <int BM, int BN, int MODE>
__global__ __launch_bounds__(256, 2) void gemm_split(
    const u16* __restrict__ Ahi, const u16* __restrict__ Alo,
    const u16* __restrict__ Bhi, const u16* __restrict__ Blo,
    const float* __restrict__ bias,
    u16* __restrict__ Chi, u16* __restrict__ Clo,
    const float* __restrict__ Wc, float* __restrict__ outp,
    int M, int N, int K) {
    constexpr int BK = 32;
    constexpr int MF = BM / 32;
    constexpr int NF = BN / 32;
    constexpr int CH_A = BM * 4;          // 16B chunks per A plane per step
    constexpr int CH_B = BN * 4;
    constexpr int CH_TOT = 2 * CH_A + 2 * CH_B;
    constexpr int LOADS = CH_TOT / 256;
    constexpr int HALF = CH_TOT * 16;
    constexpr int OFF_ALO = CH_A * 16;
    constexpr int OFF_BHI = 2 * CH_A * 16;
    constexpr int OFF_BLO = 2 * CH_A * 16 + CH_B * 16;

    __shared__ __align__(16) char smem[2 * HALF];

    const int tid = threadIdx.x;
    const int lane = tid & 63;
    const int wid = tid >> 6;
    const int wm = wid >> 1, wn = wid & 1;
    const int bm = blockIdx.x * BM;
    const int bn = blockIdx.y * BN;

    int a_off[MF], b_off[NF];
#pragma unroll
    for (int mi = 0; mi < MF; ++mi) {
        int r = wm * (BM / 2) + mi * 16 + (lane & 15);
        a_off[mi] = r * 64 + (((lane >> 4) ^ ((r >> 1) & 3)) * 16);
    }
#pragma unroll
    for (int ni = 0; ni < NF; ++ni) {
        int r = wn * (BN / 2) + ni * 16 + (lane & 15);
        b_off[ni] = r * 64 + (((lane >> 4) ^ ((r >> 1) & 3)) * 16);
    }

    f32x4 acc[MF][NF];
#pragma unroll
    for (int mi = 0; mi < MF; ++mi)
#pragma unroll
        for (int ni = 0; ni < NF; ++ni) acc[mi][ni] = {0.f, 0.f, 0.f, 0.f};

    auto stage = [&](int buf, int t) {
        const int k0 = t * BK;
#pragma unroll
        for (int j = 0; j < LOADS; ++j) {
            const int c0 = wid * (LOADS * 64) + j * 64;  // wave-uniform
            const u16* base; int pstart, row0;
            if (c0 < CH_A)                 { base = Ahi; pstart = 0;              row0 = bm; }
            else if (c0 < 2 * CH_A)        { base = Alo; pstart = CH_A;           row0 = bm; }
            else if (c0 < 2 * CH_A + CH_B) { base = Bhi; pstart = 2 * CH_A;       row0 = bn; }
            else                           { base = Blo; pstart = 2 * CH_A + CH_B; row0 = bn; }
            const int cp = c0 - pstart + lane;
            const int r = cp >> 2;
            const int s = (cp & 3) ^ ((r >> 1) & 3);     // inverse-swizzled src
            const u16* src = base + (size_t)(row0 + r) * K + k0 + 8 * s;
            gload_lds16(src, smem + buf * HALF + c0 * 16);
        }
    };

    const int T = K / BK;
    stage(0, 0);
    for (int t = 0; t < T; ++t) {
        __syncthreads();  // drains vmcnt+lgkmcnt: buf[t&1] ready
        const int buf = t & 1;
        if (t + 1 < T) stage(buf ^ 1, t + 1);
        const char* sb = smem + buf * HALF;
        short8 ah[MF], al[MF], bh[NF], bl[NF];
#pragma unroll
        for (int mi = 0; mi < MF; ++mi) {
            ah[mi] = *(const short8*)(sb + a_off[mi]);
            al[mi] = *(const short8*)(sb + OFF_ALO + a_off[mi]);
        }
#pragma unroll
        for (int ni = 0; ni < NF; ++ni) {
            bh[ni] = *(const short8*)(sb + OFF_BHI + b_off[ni]);
            bl[ni] = *(const short8*)(sb + OFF_BLO + b_off[ni]);
        }
#pragma unroll
        for (int mi = 0; mi < MF; ++mi)
#pragma unroll
            for (int ni = 0; ni < NF; ++ni) {
                acc[mi][ni] = __builtin_amdgcn_mfma_f32_16x16x32_bf16(ah[mi], bh[ni], acc[mi][ni], 0, 0, 0);
                acc[mi][ni] = __builtin_amdgcn_mfma_f32_16x16x32_bf16(ah[mi], bl[ni], acc[mi][ni], 0, 0, 0);
                acc[mi][ni] = __builtin_amdgcn_mfma_f32_16x16x32_bf16(al[mi], bh[ni], acc[mi][ni], 0, 0, 0);
            }
    }

    // epilogue: D col=lane&15, row=(lane>>4)*4+reg (m89-verified)
#pragma unroll
    for (int mi = 0; mi < MF; ++mi) {
        float hp[4] = {0.f, 0.f, 0.f, 0.f};  // MODE 3 head partials per reg-row
#pragma unroll
        for (int ni = 0; ni < NF; ++ni) {
            const int gcol = bn + wn * (BN / 2) + ni * 16 + (lane & 15);
            const float bv = bias[gcol];
            const f32x4 a = acc[mi][ni];
#pragma unroll
            for (int r = 0; r < 4; ++r) {
                const int grow = bm + wm * (BM / 2) + mi * 16 + (lane >> 4) * 4 + r;
                const float y = a[r];
                float z;
                if constexpr (MODE == 0)
                    z = lrelu(y + bv) + 2.f * lrelu(3.f * y + bv) + lrelu(5.f * y + bv);
                else
                    z = lrelu(y + bv);
                if constexpr (MODE == 3) {
                    hp[r] += z * Wc[gcol];
                } else {
                    u16 h, l; split1(z, h, l);
                    Chi[(size_t)grow * N + gcol] = h;
                    Clo[(size_t)grow * N + gcol] = l;
                }
            }
        }
        if constexpr (MODE == 3) {
            // reduce over the 16 lanes of each (lane>>4) group, then 1 atomic/row
#pragma unroll
            for (int r = 0; r < 4; ++r) {
#pragma unroll
                for (int o = 1; o < 16; o <<= 1) hp[r] += __shfl_xor(hp[r], o, 64);
            }
            if ((lane & 15) == 0) {
#pragma unroll
                for (int r = 0; r < 4; ++r) {
                    const int grow = bm + wm * (BM / 2) + mi * 16 + (lane >> 4) * 4 + r;
                    atomicAdd(outp + grow, hp[r]);
                }
            }
        }
    }
}

extern "C" void kernel_launch(void* const* d_in, const int* in_sizes, int n_in,
                              void* d_out, int out_size, void* d_ws, size_t ws_size,
                              hipStream_t stream) {
    const float* x  = (const float*)d_in[0];
    const float* W0 = (const float*)d_in[1];
    const float* b0 = (const float*)d_in[2];
    const float* W1 = (const float*)d_in[3];
    const float* b1 = (const float*)d_in[4];
    const float* W2 = (const float*)d_in[5];
    const float* b2 = (const float*)d_in[6];
    const float* Wc = (const float*)d_in[7];
    const float* bc = (const float*)d_in[8];
    float* out = (float*)d_out;

    const int Bn = 2048;

    char* w = (char*)d_ws;                 // peak ~23.6 MB
    u16* XHI  = (u16*)(w + 0);             // 4 MB
    u16* XLO  = (u16*)(w + 4194304);       // 4 MB
    u16* W0TH = (u16*)(w + 8388608);       // 2 MB
    u16* W0TL = (u16*)(w + 10485760);      // 2 MB
    u16* W1TH = (u16*)(w + 12582912);      // 1 MB
    u16* W1TL = (u16*)(w + 13631488);      // 1 MB
    u16* W2TH = (u16*)(w + 14680064);      // 256 KB
    u16* W2TL = (u16*)(w + 14942208);      // 256 KB
    u16* ZHI  = (u16*)(w + 15204352);      // 4 MB
    u16* ZLO  = (u16*)(w + 19398656);      // 4 MB
    u16* UHI  = (u16*)(w + 0);             // reuse X (dead after L0)
    u16* ULO  = (u16*)(w + 2097152);

    prep<<<2465, 256, 0, stream>>>(x, W0, W1, W2, bc, XHI, XLO, W0TH, W0TL,
                                   W1TH, W1TL, W2TH, W2TL, out);

    // L0: [2048,1024], K=1024 ; 64x64 tiles -> 512 blocks (2/CU)
    gemm_split<64, 64, 0><<<dim3(32, 16), 256, 0, stream>>>(
        XHI, XLO, W0TH, W0TL, b0, ZHI, ZLO, nullptr, nullptr, Bn, 1024, 1024);
    // L1: [2048,512], K=1024 ; 64x32 tiles -> 512 blocks
    gemm_split<64, 32, 1><<<dim3(32, 16), 256, 0, stream>>>(
        ZHI, ZLO, W1TH, W1TL, b1, UHI, ULO, nullptr, nullptr, Bn, 512, 1024);
    // L2+head: [2048,256], K=512 ; 64x32 tiles -> 256 blocks, atomics into out
    gemm_split<64, 32, 3><<<dim3(32, 8), 256, 0, stream>>>(
        UHI, ULO, W2TH, W2TL, b2, nullptr, nullptr, Wc, out, Bn, 256, 512);
}